// Round 4
// baseline (671.481 us; speedup 1.0000x reference)
//
#include <hip/hip_runtime.h>

typedef __bf16 bf16;
typedef __bf16 bf16x8 __attribute__((ext_vector_type(8)));
typedef __bf16 bf16x4 __attribute__((ext_vector_type(4)));
typedef float  f32x4  __attribute__((ext_vector_type(4)));

__device__ __forceinline__ f32x4 mfma16(bf16x8 a, bf16x8 b, f32x4 c) {
    return __builtin_amdgcn_mfma_f32_16x16x32_bf16(a, b, c, 0, 0, 0);
}

__device__ __forceinline__ void gll16(const bf16* g, bf16* l) {
    __builtin_amdgcn_global_load_lds(
        (const __attribute__((address_space(1))) void*)g,
        (__attribute__((address_space(3))) void*)l, 16, 0, 0);
}

// ---------------- K0: weight repack (BqT scaled+deinterleaved, kvWT, projT) ----------------
__global__ __launch_bounds__(256) void prep_weights(
    const float* __restrict__ qkv_w, const float* __restrict__ qkv_b,
    const float* __restrict__ proj_w,
    bf16* __restrict__ BqT, bf16* __restrict__ kvWT, bf16* __restrict__ projWT,
    float* __restrict__ bkv)
{
    int i = blockIdx.x * 256 + threadIdx.x;
    if (i < 262144) {
        int c_ = i >> 9, k = i & 511;
        int c = (c_ >> 6) * 192 + (c_ & 63) * 3;
        BqT[i] = (bf16)(qkv_w[k * 1536 + c] * 0.125f);
        return;
    }
    i -= 262144;
    if (i < 131072) {
        int c2 = i >> 9, k = i & 511;
        int t = c2 >> 7, kk = (c2 >> 6) & 1, e = c2 & 63;
        int c = t * 192 + e * 3 + 1 + kk;
        kvWT[i] = (bf16)(qkv_w[k * 1536 + c]);
        return;
    }
    i -= 131072;
    if (i < 262144) {
        int c_ = i >> 9, k = i & 511;
        projWT[i] = (bf16)(proj_w[k * 512 + c_]);
        return;
    }
    i -= 262144;
    if (i < 256) {
        int t = i >> 7, kk = (i >> 6) & 1, e = i & 63;
        bkv[i] = qkv_b[t * 192 + e * 3 + 1 + kk];
    }
}

// ---------------- K0b: R = pe_w @ Wq_scaled  [3][512], bq2 = scaled qkv_b(q) + pe_b @ Wq_s ----------------
__global__ __launch_bounds__(256) void prep_r(
    const float* __restrict__ qkv_w, const float* __restrict__ qkv_b,
    const float* __restrict__ pe_w, const float* __restrict__ pe_b,
    float* __restrict__ R, float* __restrict__ bq2)
{
    int idx = blockIdx.x * 256 + threadIdx.x;   // 2048 items
    int c = idx >> 2, j = idx & 3;
    int qc = (c >> 6) * 192 + (c & 63) * 3;
    const float* wcol = qkv_w + qc;
    float s = 0.f;
    if (j < 3) {
        const float* pw = pe_w + j * 512;
        for (int k = 0; k < 512; ++k) s += pw[k] * wcol[(size_t)k * 1536];
        R[j * 512 + c] = 0.125f * s;
    } else {
        for (int k = 0; k < 512; ++k) s += pe_b[k] * wcol[(size_t)k * 1536];
        bq2[c] = 0.125f * (qkv_b[qc] + s);
    }
}

// ---------------- K0c: rel[t][3] = pos - ball mean ----------------
__global__ __launch_bounds__(64) void relprep(const float* __restrict__ pos,
                                              float* __restrict__ rel)
{
    const int t = blockIdx.x * 64 + threadIdx.x;
    float p0 = pos[(size_t)t * 3 + 0];
    float p1 = pos[(size_t)t * 3 + 1];
    float p2 = pos[(size_t)t * 3 + 2];
    float s0 = p0, s1 = p1, s2 = p2;
    #pragma unroll
    for (int m = 1; m < 64; m <<= 1) {
        s0 += __shfl_xor(s0, m);
        s1 += __shfl_xor(s1, m);
        s2 += __shfl_xor(s2, m);
    }
    rel[(size_t)t * 3 + 0] = p0 - s0 * (1.0f / 64.0f);
    rel[(size_t)t * 3 + 1] = p1 - s1 * (1.0f / 64.0f);
    rel[(size_t)t * 3 + 2] = p2 - s2 * (1.0f / 64.0f);
}

// ---------------- K1: Q = bf16(x) @ BqT^T + rel@R + bq2  (xprep folded in) ----------------
// 128x128 tile, 4 waves, BK=64. A reg-staged (f32 load -> cvt -> swizzled ds_write);
// B via global_load_lds with pre-swizzled source. XCD-chunked bid swizzle. Direct bf16 stores.
__global__ __launch_bounds__(256, 2) void qgemm(
    const float* __restrict__ X, const bf16* __restrict__ Bt,
    const float* __restrict__ rel, const float* __restrict__ R,
    const float* __restrict__ bq2, bf16* __restrict__ Qout)
{
    const int bid0 = blockIdx.x;
    const int wg = (bid0 & 7) * 512 + (bid0 >> 3);   // 4096 % 8 == 0 -> bijective
    const int ct = wg & 3;
    const int rt = wg >> 2;
    const int row0 = rt * 128, col0 = ct * 128;
    const int tid = threadIdx.x;
    const int w = tid >> 6, l = tid & 63;
    const int wr = w >> 1, wc = w & 1;
    const int l15 = l & 15, lg = l >> 4;

    __shared__ __align__(16) bf16 As[8192];
    __shared__ __align__(16) bf16 Bs[8192];
    __shared__ float relS[128][3];
    __shared__ float RS[3][128];

    if (tid < 128) {
        relS[tid][0] = rel[(size_t)(row0 + tid) * 3 + 0];
        relS[tid][1] = rel[(size_t)(row0 + tid) * 3 + 1];
        relS[tid][2] = rel[(size_t)(row0 + tid) * 3 + 2];
    } else {
        int c = tid - 128;
        RS[0][c] = R[0 * 512 + col0 + c];
        RS[1][c] = R[1 * 512 + col0 + c];
        RS[2][c] = R[2 * 512 + col0 + c];
    }

    f32x4 acc[4][4] = {};

    // B-staging source swizzle (LDS dest linear)
    int srow[4], scol[4];
    #pragma unroll
    for (int j = 0; j < 4; ++j) {
        int chunk = w * 4 + j;
        int o = chunk * 512 + l * 8;
        int r = o >> 6;
        int slot = (o & 63) >> 3;
        srow[j] = r;
        scol[j] = ((slot ^ (r & 7)) << 3);
    }
    // A reg-staging geometry: chunk j covers rows chunk*8 + (l>>3), k-group (l&7)
    const int ar_sub = l >> 3;          // 0..7 row within chunk
    const int ak = l & 7;               // k-group
    const int aslot = (ak ^ ar_sub) << 3;

    for (int ks = 0; ks < 512; ks += 64) {
        // A: load 8 f32, cvt, swizzled ds_write_b128
        #pragma unroll
        for (int j = 0; j < 4; ++j) {
            int chunk = w * 4 + j;
            int r = chunk * 8 + ar_sub;
            const float* xp = X + (size_t)(row0 + r) * 512 + ks + ak * 8;
            float4 v0 = *(const float4*)xp;
            float4 v1 = *(const float4*)(xp + 4);
            bf16x8 bv = { (bf16)v0.x, (bf16)v0.y, (bf16)v0.z, (bf16)v0.w,
                          (bf16)v1.x, (bf16)v1.y, (bf16)v1.z, (bf16)v1.w };
            *(bf16x8*)&As[r * 64 + aslot] = bv;
        }
        // B: async global->LDS, pre-swizzled source
        #pragma unroll
        for (int j = 0; j < 4; ++j) {
            int chunk = w * 4 + j;
            gll16(Bt + (size_t)(col0 + srow[j]) * 512 + ks + scol[j], &Bs[chunk * 512]);
        }
        __syncthreads();
        #pragma unroll
        for (int kk = 0; kk < 2; ++kk) {
            bf16x8 a[4], b[4];
            #pragma unroll
            for (int mi = 0; mi < 4; ++mi) {
                int r = wr * 64 + mi * 16 + l15;
                int slot = (kk * 4 + lg) ^ (r & 7);
                a[mi] = *(const bf16x8*)&As[r * 64 + slot * 8];
            }
            #pragma unroll
            for (int ni = 0; ni < 4; ++ni) {
                int r = wc * 64 + ni * 16 + l15;
                int slot = (kk * 4 + lg) ^ (r & 7);
                b[ni] = *(const bf16x8*)&Bs[r * 64 + slot * 8];
            }
            #pragma unroll
            for (int mi = 0; mi < 4; ++mi)
                #pragma unroll
                for (int ni = 0; ni < 4; ++ni)
                    acc[mi][ni] = mfma16(a[mi], b[ni], acc[mi][ni]);
        }
        __syncthreads();
    }

    #pragma unroll
    for (int mi = 0; mi < 4; ++mi) {
        #pragma unroll
        for (int ni = 0; ni < 4; ++ni) {
            int colL = wc * 64 + ni * 16 + l15;
            int col = col0 + colL;
            float bv = bq2[col];
            float r0c = RS[0][colL], r1c = RS[1][colL], r2c = RS[2][colL];
            int rbaseL = wr * 64 + mi * 16 + lg * 4;
            #pragma unroll
            for (int r = 0; r < 4; ++r) {
                int rowL = rbaseL + r;
                float vv = acc[mi][ni][r] + bv
                         + relS[rowL][0] * r0c + relS[rowL][1] * r1c + relS[rowL][2] * r2c;
                Qout[(size_t)(row0 + rowL) * 512 + col] = (bf16)vv;
            }
        }
    }
}

// ---------------- K2: k_sel / v_selT (x' recomputed inline for 1024 tokens) ----------------
__global__ __launch_bounds__(256) void kv_proj2(
    const float* __restrict__ x, const float* __restrict__ rel,
    const float* __restrict__ pe_w, const float* __restrict__ pe_b,
    const bf16* __restrict__ kvWT, const float* __restrict__ bkv,
    bf16* __restrict__ ksel, bf16* __restrict__ vselT)
{
    const int bid = blockIdx.x;      // 1024 = 2 b * 8 balls * 64 m2
    const int b = bid >> 9;
    const int ball = (bid >> 6) & 7;
    const int m2 = bid & 63;
    const size_t tok = (size_t)b * 65536 + ball * 64 + m2;
    const int tid = threadIdx.x;

    __shared__ __align__(16) bf16 xrow[512];
    __shared__ float relt[3];
    if (tid < 3) relt[tid] = rel[tok * 3 + tid];
    __syncthreads();
    for (int k = tid; k < 512; k += 256) {
        float v = x[tok * 512 + k] + relt[0] * pe_w[k] + relt[1] * pe_w[512 + k]
                + relt[2] * pe_w[1024 + k] + pe_b[k];
        xrow[k] = (bf16)v;
    }
    __syncthreads();

    float acc = 0.f;
    const bf16* wrp = kvWT + (size_t)tid * 512;
    #pragma unroll 8
    for (int k = 0; k < 512; k += 8) {
        bf16x8 wv = *(const bf16x8*)(wrp + k);
        bf16x8 xv = *(const bf16x8*)(&xrow[k]);
        #pragma unroll
        for (int j = 0; j < 8; ++j) acc += (float)xv[j] * (float)wv[j];
    }
    acc += bkv[tid];
    int t = tid >> 7, kk = (tid >> 6) & 1, e = tid & 63;
    if (kk == 0)
        ksel[((size_t)(b * 8 + ball) * 128 + t * 64 + m2) * 64 + e] = (bf16)acc;
    else
        vselT[((size_t)(b * 8 + ball) * 64 + e) * 128 + t * 64 + m2] = (bf16)acc;
}

// ---------------- K3: fused attention + output projection ----------------
// block = 64 tokens; loop h: stage K/V -> QK^T -> softmax -> swapped PV (O^T) ->
// LDS bounce into A-frag layout -> out += O_h @ projT[h-slice].
// Wave w owns out cols [w*128, w*128+128); proj B-frags straight from L2.
__global__ __launch_bounds__(256, 2) void attnproj(
    const bf16* __restrict__ Q, const bf16* __restrict__ ksel,
    const bf16* __restrict__ vselT, const bf16* __restrict__ projT,
    const float* __restrict__ proj_b, float* __restrict__ out)
{
    const int bid = blockIdx.x;                  // 2048
    const int wg = (bid & 7) * 256 + (bid >> 3); // bijective XCD swizzle
    const int b = wg >> 10;
    const size_t tok0 = (size_t)wg * 64;
    const int tid = threadIdx.x;
    const int w = tid >> 6, l = tid & 63;
    const int l15 = l & 15, lg = l >> 4;

    __shared__ __align__(16) bf16 Ks[128][72];
    __shared__ __align__(16) bf16 Vt[64][136];
    __shared__ __align__(16) bf16 Pl[4][16][136];

    f32x4 acc[4][8] = {};   // [token-tile mi][col-tile nj within wave's 128]

    for (int h = 0; h < 8; ++h) {
        const bf16* kg = ksel + (size_t)(b * 8 + h) * 128 * 64;
        #pragma unroll
        for (int it = 0; it < 4; ++it) {
            int i = it * 256 + tid;
            int r = i >> 3, c8 = (i & 7) * 8;
            *(bf16x8*)&Ks[r][c8] = *(const bf16x8*)(kg + r * 64 + c8);
        }
        const bf16* vg = vselT + (size_t)(b * 8 + h) * 64 * 128;
        #pragma unroll
        for (int it = 0; it < 4; ++it) {
            int i = it * 256 + tid;
            int r = i >> 4, c8 = (i & 15) * 8;
            *(bf16x8*)&Vt[r][c8] = *(const bf16x8*)(vg + r * 128 + c8);
        }
        __syncthreads();

        // Q fragments (lane l15 = token row, lg*8 = e-slice)
        const bf16* qp = Q + (tok0 + w * 16 + l15) * 512 + h * 64 + lg * 8;
        bf16x8 qa0 = *(const bf16x8*)qp;
        bf16x8 qa1 = *(const bf16x8*)(qp + 32);

        // QK^T: S[token][kv]
        f32x4 s[8];
        #pragma unroll
        for (int kt = 0; kt < 8; ++kt) {
            f32x4 a0 = {0.f, 0.f, 0.f, 0.f};
            a0 = mfma16(qa0, *(const bf16x8*)&Ks[kt * 16 + l15][lg * 8], a0);
            a0 = mfma16(qa1, *(const bf16x8*)&Ks[kt * 16 + l15][32 + lg * 8], a0);
            s[kt] = a0;
        }

        // softmax per token row (16-lane group reduce), P -> Pl[w][token][kv]
        #pragma unroll
        for (int r = 0; r < 4; ++r) {
            float mx = s[0][r];
            #pragma unroll
            for (int kt = 1; kt < 8; ++kt) mx = fmaxf(mx, s[kt][r]);
            mx = fmaxf(mx, __shfl_xor(mx, 1));
            mx = fmaxf(mx, __shfl_xor(mx, 2));
            mx = fmaxf(mx, __shfl_xor(mx, 4));
            mx = fmaxf(mx, __shfl_xor(mx, 8));
            float sum = 0.f;
            #pragma unroll
            for (int kt = 0; kt < 8; ++kt) {
                float p = __expf(s[kt][r] - mx);
                s[kt][r] = p;
                sum += p;
            }
            sum += __shfl_xor(sum, 1);
            sum += __shfl_xor(sum, 2);
            sum += __shfl_xor(sum, 4);
            sum += __shfl_xor(sum, 8);
            float inv = 1.0f / sum;
            int prow = lg * 4 + r;
            #pragma unroll
            for (int kt = 0; kt < 8; ++kt)
                Pl[w][prow][kt * 16 + l15] = (bf16)(s[kt][r] * inv);
        }

        // swapped PV: O^T[e][token] = sum_kv V^T[e][kv] * P[token][kv]
        f32x4 o[4] = { {0,0,0,0}, {0,0,0,0}, {0,0,0,0}, {0,0,0,0} };
        #pragma unroll
        for (int kvc = 0; kvc < 4; ++kvc) {
            bf16x8 pb_ = *(const bf16x8*)&Pl[w][l15][kvc * 32 + lg * 8];
            #pragma unroll
            for (int et = 0; et < 4; ++et)
                o[et] = mfma16(*(const bf16x8*)&Vt[et * 16 + l15][kvc * 32 + lg * 8], pb_, o[et]);
        }

        // bounce O into A-frag layout: Pl[w][token=l15][e]
        #pragma unroll
        for (int et = 0; et < 4; ++et)
            #pragma unroll
            for (int r = 0; r < 4; ++r)
                Pl[w][l15][et * 16 + lg * 4 + r] = (bf16)(o[et][r]);

        __syncthreads();

        // proj accumulate: wave w covers out cols [w*128, w*128+128)
        #pragma unroll
        for (int kc = 0; kc < 2; ++kc) {
            bf16x8 af[4];
            #pragma unroll
            for (int mi = 0; mi < 4; ++mi)
                af[mi] = *(const bf16x8*)&Pl[mi][l15][kc * 32 + lg * 8];
            #pragma unroll
            for (int nj = 0; nj < 8; ++nj) {
                const bf16* bp = projT + (size_t)(w * 128 + nj * 16 + l15) * 512
                               + h * 64 + kc * 32 + lg * 8;
                bf16x8 bf_ = *(const bf16x8*)bp;
                #pragma unroll
                for (int mi = 0; mi < 4; ++mi)
                    acc[mi][nj] = mfma16(af[mi], bf_, acc[mi][nj]);
            }
        }
        __syncthreads();
    }

    // epilogue: direct f32 stores
    #pragma unroll
    for (int nj = 0; nj < 8; ++nj) {
        int col = w * 128 + nj * 16 + l15;
        float bv = proj_b[col];
        #pragma unroll
        for (int mi = 0; mi < 4; ++mi) {
            size_t rbase = tok0 + mi * 16 + lg * 4;
            #pragma unroll
            for (int r = 0; r < 4; ++r)
                out[(rbase + r) * 512 + col] = acc[mi][nj][r] + bv;
        }
    }
}

extern "C" void kernel_launch(void* const* d_in, const int* in_sizes, int n_in,
                              void* d_out, int out_size, void* d_ws, size_t ws_size,
                              hipStream_t stream) {
    (void)in_sizes; (void)n_in; (void)out_size; (void)ws_size;
    const float* x      = (const float*)d_in[0];
    const float* pos    = (const float*)d_in[1];
    const float* qkv_w  = (const float*)d_in[2];
    const float* qkv_b  = (const float*)d_in[3];
    const float* proj_w = (const float*)d_in[4];
    const float* proj_b = (const float*)d_in[5];
    const float* pe_w   = (const float*)d_in[6];
    const float* pe_b   = (const float*)d_in[7];

    char* ws = (char*)d_ws;
    bf16*  Q     = (bf16*)(ws);                          // 134217728
    bf16*  BqT   = (bf16*)(ws + 134217728);              // 524288
    bf16*  PjT   = (bf16*)(ws + 134742016);              // 524288
    bf16*  kvWT  = (bf16*)(ws + 135266304);              // 262144
    bf16*  ksel  = (bf16*)(ws + 135528448);              // 262144
    bf16*  vselT = (bf16*)(ws + 135790592);              // 262144
    float* rel   = (float*)(ws + 136052736);             // 1572864
    float* R     = (float*)(ws + 137625600);             // 6144
    float* bq2   = (float*)(ws + 137631744);             // 2048
    float* bkv   = (float*)(ws + 137633792);             // 1024

    prep_weights<<<2561, 256, 0, stream>>>(qkv_w, qkv_b, proj_w, BqT, kvWT, PjT, bkv);
    prep_r<<<8, 256, 0, stream>>>(qkv_w, qkv_b, pe_w, pe_b, R, bq2);
    relprep<<<2048, 64, 0, stream>>>(pos, rel);
    qgemm<<<4096, 256, 0, stream>>>(x, BqT, rel, R, bq2, Q);
    kv_proj2<<<1024, 256, 0, stream>>>(x, rel, pe_w, pe_b, kvWT, bkv, ksel, vselT);
    attnproj<<<2048, 256, 0, stream>>>(Q, ksel, vselT, PjT, proj_b, (float*)d_out);
}